// Round 5
// baseline (756.520 us; speedup 1.0000x reference)
//
#include <hip/hip_runtime.h>
#include <hip/hip_bf16.h>
#include <stdint.h>

#define D_ 1024
#define H_ 16
#define DH_ 64
#define S_ 2048
#define B_ 16
static constexpr float SCALE = 0.125f;  // 1/sqrt(64)

typedef __bf16 bf16_t;
typedef __bf16 bf16x8 __attribute__((ext_vector_type(8)));
typedef __bf16 bf16x4 __attribute__((ext_vector_type(4)));
typedef float  f32x4  __attribute__((ext_vector_type(4)));

__device__ __forceinline__ void llds16(const void* g, void* l) {
  __builtin_amdgcn_global_load_lds(
      (const __attribute__((address_space(1))) void*)g,
      (__attribute__((address_space(3))) void*)l, 16, 0, 0);
}

// ---------------------------------------------------------------------------
// hidden_states f32 -> bf16
// ---------------------------------------------------------------------------
__global__ __launch_bounds__(256)
void f32_to_bf16(const float* __restrict__ src, bf16_t* __restrict__ dst) {
  size_t base = ((size_t)blockIdx.x * 256 + threadIdx.x) * 8;
  f32x4 a = *(const f32x4*)&src[base];
  f32x4 b = *(const f32x4*)&src[base + 4];
  bf16x8 o;
#pragma unroll
  for (int i = 0; i < 4; ++i) { o[i] = (bf16_t)a[i]; o[4 + i] = (bf16_t)b[i]; }
  *(bf16x8*)&dst[base] = o;
}

// ---------------------------------------------------------------------------
// 1024x1024 f32 -> bf16 transpose: dst[n][k] = src[k][n]
// ---------------------------------------------------------------------------
__global__ __launch_bounds__(256)
void transpose1024(const float* __restrict__ src, bf16_t* __restrict__ dst) {
  __shared__ bf16_t t[64][65];
  const int n0 = blockIdx.x * 64, k0 = blockIdx.y * 64;
  const int r = threadIdx.x >> 4, c4 = (threadIdx.x & 15) * 4;
#pragma unroll
  for (int p = 0; p < 4; ++p) {
    int row = p * 16 + r;
    f32x4 f = *(const f32x4*)&src[(size_t)(k0 + row) * 1024 + n0 + c4];
#pragma unroll
    for (int i = 0; i < 4; ++i) t[row][c4 + i] = (bf16_t)f[i];
  }
  __syncthreads();
#pragma unroll
  for (int p = 0; p < 4; ++p) {
    int row = p * 16 + r;
    bf16x4 v;
#pragma unroll
    for (int i = 0; i < 4; ++i) v[i] = t[c4 + i][row];
    *(bf16x4*)&dst[(size_t)(n0 + row) * 1024 + k0 + c4] = v;
  }
}

// [1024][16] f32 -> [16][1024] bf16
__global__ __launch_bounds__(256)
void transpose_small(const float* __restrict__ src, bf16_t* __restrict__ dst) {
  int k = blockIdx.x * 256 + threadIdx.x;
  if (k < 1024) {
#pragma unroll
    for (int h = 0; h < H_; ++h) dst[h * 1024 + k] = (bf16_t)src[k * H_ + h];
  }
}

// small biases + mask f32 -> bf16 (for score kernels)
__global__ __launch_bounds__(256)
void conv_misc(const float* bqa, const float* bka, const float* mask,
               bf16_t* obqa, bf16_t* obka, bf16_t* omask) {
  int i = blockIdx.x * 256 + threadIdx.x;
  const float* src; bf16_t* dst; int off;
  if      (i < 16)    { src = bqa;  dst = obqa;  off = i; }
  else if (i < 32)    { src = bka;  dst = obka;  off = i - 16; }
  else if (i < 32800) { src = mask; dst = omask; off = i - 32; }
  else return;
  dst[off] = (bf16_t)src[off];
}

// ---------------------------------------------------------------------------
// 256x256-tile pipelined GEMM: C[M][1024] = A[M][1024] @ BT[1024][1024]^T
// + bias (+epilogue). Counted-vmcnt dbuf pipeline, T2 XOR swizzle, T5 setprio,
// LDS-staged coalesced epilogue.
// MODE 0: -> bf16 (mixed_q); MODE 1: *pscale -> bf16 (mixed_qk);
// MODE 2: +resid -> f32 (final output)
// ---------------------------------------------------------------------------
template <int MODE>
__global__ __launch_bounds__(512, 2)
void gemm256(const bf16_t* __restrict__ A, const bf16_t* __restrict__ BT,
             const float* __restrict__ bias, void* __restrict__ Cout,
             const float* __restrict__ pscale, const bf16_t* __restrict__ resid) {
  constexpr int K = 1024;
  // lds[buf][0]=A-tile 256x64, lds[buf][1]=B-tile 256x64  (128 KiB total)
  __shared__ __align__(16) bf16_t lds[2][2][256 * 64];
  const int tid = threadIdx.x;
  const int lane = tid & 63, wid = tid >> 6;   // 8 waves
  const int wm = wid >> 2, wn = wid & 3;       // 2 x 4 wave grid

  // XCD-aware swizzle: nwg=512, 512%8==0 -> 64 contiguous ids per XCD
  const int wgid = (blockIdx.x & 7) * 64 + (blockIdx.x >> 3);
  const int m0 = (wgid >> 2) * 256;
  const int n0 = (wgid & 3) * 256;

  // staging chunks: 4 per thread per matrix; chunk c -> row c>>3, slot c&7;
  // slot j holds global col-chunk j^(row&7)  (T2 involution swizzle)
  const bf16_t* gA[4];
  const bf16_t* gB[4];
  int ldsOff[4];
#pragma unroll
  for (int i = 0; i < 4; ++i) {
    int c = i * 512 + tid;
    int r = c >> 3, j = c & 7;
    int col = ((j ^ (r & 7)) << 3);
    gA[i] = A  + (size_t)(m0 + r) * K + col;
    gB[i] = BT + (size_t)(n0 + r) * K + col;
    ldsOff[i] = c * 8;
  }

  f32x4 acc[8][4] = {};
  const int ar = lane & 15;
  const int kq = lane >> 4;  // k-quarter within frag

  // prologue: stage tiles 0,1
#pragma unroll
  for (int i = 0; i < 4; ++i) { llds16(gA[i], &lds[0][0][ldsOff[i]]); llds16(gB[i], &lds[0][1][ldsOff[i]]); }
#pragma unroll
  for (int i = 0; i < 4; ++i) { llds16(gA[i] + 64, &lds[1][0][ldsOff[i]]); llds16(gB[i] + 64, &lds[1][1][ldsOff[i]]); }

#pragma unroll 2
  for (int t = 0; t < 16; ++t) {
    const int cur = t & 1;
    if (t < 15) asm volatile("s_waitcnt vmcnt(8)" ::: "memory");
    else        asm volatile("s_waitcnt vmcnt(0)" ::: "memory");
    __builtin_amdgcn_s_barrier();

    const bf16_t* bufA = &lds[cur][0][0];
    const bf16_t* bufB = &lds[cur][1][0];
    bf16x8 af[8], bg[4];
    // ----- kstep 0 frags + MFMA -----
#pragma unroll
    for (int m = 0; m < 8; ++m) {
      int r = wm * 128 + m * 16 + ar;
      af[m] = *(const bf16x8*)&bufA[r * 64 + (((kq) ^ (r & 7)) << 3)];
    }
#pragma unroll
    for (int n = 0; n < 4; ++n) {
      int r = wn * 64 + n * 16 + ar;
      bg[n] = *(const bf16x8*)&bufB[r * 64 + (((kq) ^ (r & 7)) << 3)];
    }
    __builtin_amdgcn_s_setprio(1);
#pragma unroll
    for (int m = 0; m < 8; ++m)
#pragma unroll
      for (int n = 0; n < 4; ++n)
        acc[m][n] = __builtin_amdgcn_mfma_f32_16x16x32_bf16(af[m], bg[n], acc[m][n], 0, 0, 0);
    __builtin_amdgcn_s_setprio(0);
    // ----- kstep 1 frags -----
#pragma unroll
    for (int m = 0; m < 8; ++m) {
      int r = wm * 128 + m * 16 + ar;
      af[m] = *(const bf16x8*)&bufA[r * 64 + (((kq + 4) ^ (r & 7)) << 3)];
    }
#pragma unroll
    for (int n = 0; n < 4; ++n) {
      int r = wn * 64 + n * 16 + ar;
      bg[n] = *(const bf16x8*)&bufB[r * 64 + (((kq + 4) ^ (r & 7)) << 3)];
    }
    asm volatile("s_waitcnt lgkmcnt(0)" ::: "memory");
    __builtin_amdgcn_s_barrier();   // all waves done reading buf[cur]
    if (t + 2 < 16) {               // stage tile t+2 into buf[cur]
      const int koff = (t + 2) * 64;
      bf16_t* dA = &lds[cur][0][0];
      bf16_t* dB = &lds[cur][1][0];
#pragma unroll
      for (int i = 0; i < 4; ++i) { llds16(gA[i] + koff, dA + ldsOff[i]); llds16(gB[i] + koff, dB + ldsOff[i]); }
    }
    __builtin_amdgcn_s_setprio(1);
#pragma unroll
    for (int m = 0; m < 8; ++m)
#pragma unroll
      for (int n = 0; n < 4; ++n)
        acc[m][n] = __builtin_amdgcn_mfma_f32_16x16x32_bf16(af[m], bg[n], acc[m][n], 0, 0, 0);
    __builtin_amdgcn_s_setprio(0);
  }

  // ----- epilogue: LDS-staged coalesced stores -----
  // per-wave private slice: 16 rows x 68 f32 (4352 B); all reads of lds done
  // workgroup-wide at the final mid-barrier above.
  float* st = (float*)(&lds[0][0][0]) + wid * (16 * 68);
  const int b = m0 / S_;
  const int erow = lane >> 2;          // 0..15
  const int ecol = (lane & 3) * 16;    // 0,16,32,48
  const int gcb = n0 + wn * 64;        // wave col base
  const int qrow = (lane >> 4) * 4;
  const int qcol = lane & 15;
  f32x4 bb[4], ps[4];
#pragma unroll
  for (int q = 0; q < 4; ++q) bb[q] = *(const f32x4*)&bias[gcb + ecol + q * 4];
  if (MODE == 1) {
#pragma unroll
    for (int q = 0; q < 4; ++q) ps[q] = *(const f32x4*)&pscale[b * D_ + gcb + ecol + q * 4];
  }
#pragma unroll
  for (int m = 0; m < 8; ++m) {
#pragma unroll
    for (int n = 0; n < 4; ++n)
#pragma unroll
      for (int j = 0; j < 4; ++j)
        st[(qrow + j) * 68 + n * 16 + qcol] = acc[m][n][j];
    asm volatile("s_waitcnt lgkmcnt(0)" ::: "memory");
    const int grow = m0 + wm * 128 + m * 16 + erow;
    f32x4 v[4];
#pragma unroll
    for (int q = 0; q < 4; ++q) v[q] = *(f32x4*)&st[erow * 68 + ecol + q * 4];
#pragma unroll
    for (int q = 0; q < 4; ++q)
#pragma unroll
      for (int i = 0; i < 4; ++i) v[q][i] += bb[q][i];
    if (MODE == 1) {
#pragma unroll
      for (int q = 0; q < 4; ++q)
#pragma unroll
        for (int i = 0; i < 4; ++i) v[q][i] *= ps[q][i];
    }
    if (MODE == 2) {
      bf16x8 r0 = *(const bf16x8*)&resid[(size_t)grow * D_ + gcb + ecol];
      bf16x8 r1 = *(const bf16x8*)&resid[(size_t)grow * D_ + gcb + ecol + 8];
#pragma unroll
      for (int i = 0; i < 4; ++i) { v[0][i] += (float)r0[i]; v[1][i] += (float)r0[4 + i]; }
#pragma unroll
      for (int i = 0; i < 4; ++i) { v[2][i] += (float)r1[i]; v[3][i] += (float)r1[4 + i]; }
      float* op = (float*)Cout + (size_t)grow * D_ + gcb + ecol;
#pragma unroll
      for (int q = 0; q < 4; ++q) *(f32x4*)&op[q * 4] = v[q];
    } else {
      bf16x8 o0, o1;
#pragma unroll
      for (int i = 0; i < 4; ++i) { o0[i] = (bf16_t)v[0][i]; o0[4 + i] = (bf16_t)v[1][i]; }
#pragma unroll
      for (int i = 0; i < 4; ++i) { o1[i] = (bf16_t)v[2][i]; o1[4 + i] = (bf16_t)v[3][i]; }
      bf16_t* op = (bf16_t*)Cout + (size_t)grow * D_ + gcb + ecol;
      *(bf16x8*)&op[0] = o0;
      *(bf16x8*)&op[8] = o1;
    }
    // next m overwrites the slice; same-wave DS ops are in-order + compiler
    // orders via aliasing, so no barrier needed.
  }
}

// ---------------------------------------------------------------------------
// scores[b*H+h][s] = (X[b,s,:] . WaT[h,:] + ba[h]) * SCALE + mask[b][s]
// ---------------------------------------------------------------------------
__global__ __launch_bounds__(256)
void score_kernel(const bf16_t* __restrict__ X, const bf16_t* __restrict__ WaT,
                  const bf16_t* __restrict__ ba, const bf16_t* __restrict__ mask,
                  float* __restrict__ scores) {
  const int lane = threadIdx.x & 63, wid = threadIdx.x >> 6;
  const int m0 = blockIdx.x * 64 + wid * 16;
  const int ar = lane & 15, ak = (lane >> 4) * 8;
  f32x4 acc = {};
  for (int k0 = 0; k0 < D_; k0 += 32) {
    bf16x8 a = *(const bf16x8*)&X[(size_t)(m0 + ar) * D_ + k0 + ak];
    bf16x8 b = *(const bf16x8*)&WaT[(size_t)ar * D_ + k0 + ak];
    acc = __builtin_amdgcn_mfma_f32_16x16x32_bf16(a, b, acc, 0, 0, 0);
  }
  const int h = lane & 15;
  const int srow = m0 + (lane >> 4) * 4;
  const int bb = srow / S_;
  const int s0 = srow - bb * S_;
  const float bah = (float)ba[h];
  f32x4 outv;
#pragma unroll
  for (int j = 0; j < 4; ++j)
    outv[j] = (acc[j] + bah) * SCALE + (float)mask[(size_t)bb * S_ + s0 + j];
  *(f32x4*)&scores[((size_t)(bb * H_ + h)) * S_ + s0] = outv;
}

// ---------------------------------------------------------------------------
// softmax over each scores row -> normalized weights
// ---------------------------------------------------------------------------
__global__ __launch_bounds__(256)
void softmax_rows(const float* __restrict__ scores, float* __restrict__ wout) {
  __shared__ float rA[4], rB[4];
  const int tid = threadIdx.x, lane = tid & 63, wid = tid >> 6;
  const float* srow = scores + (size_t)blockIdx.x * S_;
  float* wrow = wout + (size_t)blockIdx.x * S_;
  f32x4 v0 = *(const f32x4*)&srow[tid * 4];
  f32x4 v1 = *(const f32x4*)&srow[1024 + tid * 4];
  float mx = fmaxf(fmaxf(fmaxf(v0[0], v0[1]), fmaxf(v0[2], v0[3])),
                   fmaxf(fmaxf(v1[0], v1[1]), fmaxf(v1[2], v1[3])));
#pragma unroll
  for (int o = 32; o; o >>= 1) mx = fmaxf(mx, __shfl_xor(mx, o));
  if (lane == 0) rA[wid] = mx;
  __syncthreads();
  mx = fmaxf(fmaxf(rA[0], rA[1]), fmaxf(rA[2], rA[3]));
  float sum = 0.f;
#pragma unroll
  for (int i = 0; i < 4; ++i) { v0[i] = __expf(v0[i] - mx); sum += v0[i]; }
#pragma unroll
  for (int i = 0; i < 4; ++i) { v1[i] = __expf(v1[i] - mx); sum += v1[i]; }
#pragma unroll
  for (int o = 32; o; o >>= 1) sum += __shfl_xor(sum, o);
  if (lane == 0) rB[wid] = sum;
  __syncthreads();
  sum = rB[0] + rB[1] + rB[2] + rB[3];
  const float inv = 1.0f / sum;
#pragma unroll
  for (int i = 0; i < 4; ++i) { v0[i] *= inv; v1[i] *= inv; }
  *(f32x4*)&wrow[tid * 4] = v0;
  *(f32x4*)&wrow[1024 + tid * 4] = v1;
}

// ---------------------------------------------------------------------------
// pool partials over 32-row chunks (coalesced bf16x8)
// ---------------------------------------------------------------------------
__global__ __launch_bounds__(256)
void pool_partial(const bf16_t* __restrict__ X, const float* __restrict__ w,
                  float* __restrict__ partials) {
  __shared__ float sm[2][1024];
  const int tid = threadIdx.x;
  const int chunk = blockIdx.x, b = blockIdx.y;
  const int s0 = chunk * 32;
  const int dc = (tid & 127) * 8;
  const int sp = tid >> 7;
  const int h = dc >> 6;
  const float* wrow = w + ((size_t)b * H_ + h) * S_ + s0;
  const bf16_t* Xb = X + ((size_t)b * S_ + s0) * D_ + dc;
  float acc[8] = {};
  for (int s = sp; s < 32; s += 2) {
    bf16x8 xv = *(const bf16x8*)&Xb[(size_t)s * D_];
    float wt = wrow[s];
#pragma unroll
    for (int j = 0; j < 8; ++j) acc[j] += wt * (float)xv[j];
  }
#pragma unroll
  for (int j = 0; j < 8; ++j) sm[sp][dc + j] = acc[j];
  __syncthreads();
  const int d0 = tid * 4;
  f32x4 r;
#pragma unroll
  for (int j = 0; j < 4; ++j) r[j] = sm[0][d0 + j] + sm[1][d0 + j];
  *(f32x4*)&partials[((size_t)chunk * B_ + b) * D_ + d0] = r;
}

__global__ __launch_bounds__(256)
void pool_reduce(const float* __restrict__ partials, float* __restrict__ pooled) {
  const int idx = blockIdx.x * 256 + threadIdx.x;
  float s = 0.f;
#pragma unroll 8
  for (int c = 0; c < 64; ++c) s += partials[(size_t)c * (B_ * D_) + idx];
  pooled[idx] = s;
}

// ---------------------------------------------------------------------------
// weighted[b,s,d] = mq[b,s,d] * pk[b][d]
// ---------------------------------------------------------------------------
__global__ __launch_bounds__(256)
void weighted_kernel(const bf16_t* __restrict__ mq, const float* __restrict__ pk,
                     bf16_t* __restrict__ out) {
  size_t idx = ((size_t)blockIdx.x * 256 + threadIdx.x) * 8;
  int d0 = (int)(idx & (D_ - 1));
  int b = (int)(idx >> 21);
  bf16x8 v = *(const bf16x8*)&mq[idx];
  const float* pkb = pk + (size_t)b * D_ + d0;
  bf16x8 o;
#pragma unroll
  for (int i = 0; i < 8; ++i) o[i] = (bf16_t)((float)v[i] * pkb[i]);
  *(bf16x8*)&out[idx] = o;
}

// ---------------------------------------------------------------------------
extern "C" void kernel_launch(void* const* d_in, const int* in_sizes, int n_in,
                              void* d_out, int out_size, void* d_ws, size_t ws_size,
                              hipStream_t stream) {
  const float* hs   = (const float*)d_in[0];
  const float* mask = (const float*)d_in[1];
  const float* Wq   = (const float*)d_in[2];
  const float* bq   = (const float*)d_in[3];
  const float* Wqa  = (const float*)d_in[4];
  const float* bqa  = (const float*)d_in[5];
  const float* Wk   = (const float*)d_in[6];
  const float* bk   = (const float*)d_in[7];
  const float* Wka  = (const float*)d_in[8];
  const float* bka  = (const float*)d_in[9];
  const float* Wt   = (const float*)d_in[10];
  const float* bt   = (const float*)d_in[11];

  char* ws = (char*)d_ws;
  float*  pq    = (float*)(ws + (64u << 10));
  float*  pk    = (float*)(ws + (128u << 10));
  bf16_t* bqac  = (bf16_t*)(ws + (192u << 10));
  bf16_t* bkac  = (bf16_t*)(ws + (192u << 10) + 64);
  bf16_t* maskc = (bf16_t*)(ws + (256u << 10));
  bf16_t* WqaT  = (bf16_t*)(ws + (1u << 20));
  bf16_t* WkaT  = (bf16_t*)(ws + (1u << 20) + 32768);
  bf16_t* WqT   = (bf16_t*)(ws + (2u << 20));
  bf16_t* WkT   = (bf16_t*)(ws + (4u << 20));
  bf16_t* WtT   = (bf16_t*)(ws + (6u << 20));
  bf16_t* hsb   = (bf16_t*)(ws + (8u << 20));
  bf16_t* mq    = (bf16_t*)(ws + (8u << 20) + ((size_t)64 << 20));
  bf16_t* mqk   = (bf16_t*)(ws + (8u << 20) + ((size_t)128 << 20));
  bf16_t* wtd   = (bf16_t*)(ws + (8u << 20) + ((size_t)192 << 20));
  float* scores = (float*)(ws + (8u << 20) + ((size_t)256 << 20));
  float* wsm    = (float*)(ws + (8u << 20) + ((size_t)258 << 20));
  float* parts  = (float*)(ws + (8u << 20) + ((size_t)260 << 20));

  // prep
  f32_to_bf16<<<16384, 256, 0, stream>>>(hs, hsb);
  conv_misc<<<129, 256, 0, stream>>>(bqa, bka, mask, bqac, bkac, maskc);
  transpose1024<<<dim3(16, 16), 256, 0, stream>>>(Wq, WqT);
  transpose1024<<<dim3(16, 16), 256, 0, stream>>>(Wk, WkT);
  transpose1024<<<dim3(16, 16), 256, 0, stream>>>(Wt, WtT);
  transpose_small<<<4, 256, 0, stream>>>(Wqa, WqaT);
  transpose_small<<<4, 256, 0, stream>>>(Wka, WkaT);

  // mixed_q = hs @ Wq + bq
  gemm256<0><<<512, 512, 0, stream>>>(hsb, WqT, bq, mq, nullptr, nullptr);

  score_kernel<<<512, 256, 0, stream>>>(mq, WqaT, bqac, maskc, scores);
  softmax_rows<<<256, 256, 0, stream>>>(scores, wsm);
  pool_partial<<<dim3(64, 16), 256, 0, stream>>>(mq, wsm, parts);
  pool_reduce<<<64, 256, 0, stream>>>(parts, pq);

  // mixed_qk = (hs @ Wk + bk) * pooled_q
  gemm256<1><<<512, 512, 0, stream>>>(hsb, WkT, bk, mqk, pq, nullptr);

  score_kernel<<<512, 256, 0, stream>>>(mqk, WkaT, bkac, maskc, scores);
  softmax_rows<<<256, 256, 0, stream>>>(scores, wsm);
  pool_partial<<<dim3(64, 16), 256, 0, stream>>>(mqk, wsm, parts);
  pool_reduce<<<64, 256, 0, stream>>>(parts, pk);

  // weighted = mq * pooled_k
  weighted_kernel<<<16384, 256, 0, stream>>>(mq, pk, wtd);

  // out = weighted @ Wt + bt + mixed_q   (f32 out)
  gemm256<2><<<512, 512, 0, stream>>>(wtd, WtT, bt, d_out, nullptr, mq);
}

// Round 6
// 412.988 us; speedup vs baseline: 1.8318x; 1.8318x over previous
//
#include <hip/hip_runtime.h>
#include <hip/hip_bf16.h>
#include <stdint.h>

#define D_ 1024
#define H_ 16
#define DH_ 64
#define S_ 2048
#define B_ 16
static constexpr float SCALE = 0.125f;  // 1/sqrt(64)

typedef __bf16 bf16_t;
typedef __bf16 bf16x8 __attribute__((ext_vector_type(8)));
typedef __bf16 bf16x4 __attribute__((ext_vector_type(4)));
typedef float  f32x4  __attribute__((ext_vector_type(4)));

__device__ __forceinline__ void llds16(const void* g, void* l) {
  __builtin_amdgcn_global_load_lds(
      (const __attribute__((address_space(1))) void*)g,
      (__attribute__((address_space(3))) void*)l, 16, 0, 0);
}

// ---------------------------------------------------------------------------
// hidden_states f32 -> bf16
// ---------------------------------------------------------------------------
__global__ __launch_bounds__(256)
void f32_to_bf16(const float* __restrict__ src, bf16_t* __restrict__ dst) {
  size_t base = ((size_t)blockIdx.x * 256 + threadIdx.x) * 8;
  f32x4 a = *(const f32x4*)&src[base];
  f32x4 b = *(const f32x4*)&src[base + 4];
  bf16x8 o;
#pragma unroll
  for (int i = 0; i < 4; ++i) { o[i] = (bf16_t)a[i]; o[4 + i] = (bf16_t)b[i]; }
  *(bf16x8*)&dst[base] = o;
}

// ---------------------------------------------------------------------------
// 1024x1024 f32 -> bf16 transpose: dst[n][k] = src[k][n]
// ---------------------------------------------------------------------------
__global__ __launch_bounds__(256)
void transpose1024(const float* __restrict__ src, bf16_t* __restrict__ dst) {
  __shared__ bf16_t t[64][65];
  const int n0 = blockIdx.x * 64, k0 = blockIdx.y * 64;
  const int r = threadIdx.x >> 4, c4 = (threadIdx.x & 15) * 4;
#pragma unroll
  for (int p = 0; p < 4; ++p) {
    int row = p * 16 + r;
    f32x4 f = *(const f32x4*)&src[(size_t)(k0 + row) * 1024 + n0 + c4];
#pragma unroll
    for (int i = 0; i < 4; ++i) t[row][c4 + i] = (bf16_t)f[i];
  }
  __syncthreads();
#pragma unroll
  for (int p = 0; p < 4; ++p) {
    int row = p * 16 + r;
    bf16x4 v;
#pragma unroll
    for (int i = 0; i < 4; ++i) v[i] = t[c4 + i][row];
    *(bf16x4*)&dst[(size_t)(n0 + row) * 1024 + k0 + c4] = v;
  }
}

// [1024][16] f32 -> [16][1024] bf16
__global__ __launch_bounds__(256)
void transpose_small(const float* __restrict__ src, bf16_t* __restrict__ dst) {
  int k = blockIdx.x * 256 + threadIdx.x;
  if (k < 1024) {
#pragma unroll
    for (int h = 0; h < H_; ++h) dst[h * 1024 + k] = (bf16_t)src[k * H_ + h];
  }
}

// small biases + mask f32 -> bf16 (for score kernels)
__global__ __launch_bounds__(256)
void conv_misc(const float* bqa, const float* bka, const float* mask,
               bf16_t* obqa, bf16_t* obka, bf16_t* omask) {
  int i = blockIdx.x * 256 + threadIdx.x;
  const float* src; bf16_t* dst; int off;
  if      (i < 16)    { src = bqa;  dst = obqa;  off = i; }
  else if (i < 32)    { src = bka;  dst = obka;  off = i - 16; }
  else if (i < 32800) { src = mask; dst = omask; off = i - 32; }
  else return;
  dst[off] = (bf16_t)src[off];
}

// ---------------------------------------------------------------------------
// 256x256-tile GEMM, BK=64, 8 waves (2x4), full LDS double-buffer (128 KiB).
// Per K-tile: 4 quadrant-phases {2 stage-loads -> 12 swizzled ds_read_b128 ->
// s_barrier -> setprio(1) 16 MFMA setprio(0) -> s_barrier}; ONE
// __syncthreads() (vmcnt drain) per K-tile. Race-free: staging always targets
// the buffer NOT being read; tile-boundary barrier separates read->write.
// MODE 0: -> bf16 (mixed_q); MODE 1: *pscale -> bf16 (mixed_qk);
// MODE 2: +resid -> f32 (final output)
// ---------------------------------------------------------------------------
template <int MODE>
__global__ __launch_bounds__(512, 1)
void gemm256(const bf16_t* __restrict__ A, const bf16_t* __restrict__ BT,
             const float* __restrict__ bias, void* __restrict__ Cout,
             const float* __restrict__ pscale, const bf16_t* __restrict__ resid) {
  constexpr int K = 1024;
  __shared__ __align__(16) bf16_t lds[2][2][256 * 64];
  const int tid = threadIdx.x;
  const int lane = tid & 63, wid = tid >> 6;   // 8 waves
  const int wm = wid >> 2, wn = wid & 3;       // 2 x 4 wave grid

  // XCD swizzle: nwg=512, 512%8==0 -> 64 contiguous ids per XCD
  const int wgid = (blockIdx.x & 7) * 64 + (blockIdx.x >> 3);
  const int m0 = (wgid >> 2) * 256;
  const int n0 = (wgid & 3) * 256;

  // staging: 4 chunks/thread/matrix; chunk c -> row c>>3, slot c&7;
  // slot j holds global col-chunk j^(row&7)  (T2 involution; measured 0 confl)
  const bf16_t* gA[4];
  const bf16_t* gB[4];
  int ldsOff[4];
#pragma unroll
  for (int i = 0; i < 4; ++i) {
    int c = i * 512 + tid;
    int r = c >> 3, j = c & 7;
    int col = ((j ^ (r & 7)) << 3);
    gA[i] = A  + (size_t)(m0 + r) * K + col;
    gB[i] = BT + (size_t)(n0 + r) * K + col;
    ldsOff[i] = c * 8;
  }

  f32x4 acc[8][4] = {};
  const int ar = lane & 15;
  const int kq = lane >> 4;  // 16B k-chunk within 32-k-step

  bf16_t* curA = &lds[0][0][0]; bf16_t* curB = &lds[0][1][0];
  bf16_t* nxtA = &lds[1][0][0]; bf16_t* nxtB = &lds[1][1][0];

  // prologue: stage K-tile 0
#pragma unroll
  for (int i = 0; i < 4; ++i) { llds16(gA[i], curA + ldsOff[i]); llds16(gB[i], curB + ldsOff[i]); }
  __syncthreads();

  for (int t = 0; t < 16; ++t) {
    const int koff = (t + 1) * 64;
#pragma unroll
    for (int q = 0; q < 4; ++q) {
      if (t < 15) {  // stage chunk q of tile t+1 into the OTHER buffer
        llds16(gA[q] + koff, nxtA + ldsOff[q]);
        llds16(gB[q] + koff, nxtB + ldsOff[q]);
      }
      const int mh = q >> 1, nh = q & 1;
      bf16x8 af[4][2], bg[2][2];
#pragma unroll
      for (int mm = 0; mm < 4; ++mm) {
        int r = wm * 128 + (mh * 4 + mm) * 16 + ar;
#pragma unroll
        for (int kk = 0; kk < 2; ++kk)
          af[mm][kk] = *(const bf16x8*)&curA[r * 64 + (((kk * 4 + kq) ^ (r & 7)) << 3)];
      }
#pragma unroll
      for (int nn = 0; nn < 2; ++nn) {
        int r = wn * 64 + (nh * 2 + nn) * 16 + ar;
#pragma unroll
        for (int kk = 0; kk < 2; ++kk)
          bg[nn][kk] = *(const bf16x8*)&curB[r * 64 + (((kk * 4 + kq) ^ (r & 7)) << 3)];
      }
      __builtin_amdgcn_s_barrier();       // phase-lock waves
      __builtin_amdgcn_s_setprio(1);
#pragma unroll
      for (int mm = 0; mm < 4; ++mm)
#pragma unroll
        for (int nn = 0; nn < 2; ++nn)
#pragma unroll
          for (int kk = 0; kk < 2; ++kk)
            acc[mh * 4 + mm][nh * 2 + nn] = __builtin_amdgcn_mfma_f32_16x16x32_bf16(
                af[mm][kk], bg[nn][kk], acc[mh * 4 + mm][nh * 2 + nn], 0, 0, 0);
      __builtin_amdgcn_s_setprio(0);
      if (q < 3) __builtin_amdgcn_s_barrier();
    }
    __syncthreads();  // drains vmcnt(0): tile t+1 landed; all reads of cur done
    bf16_t* tA = curA; curA = nxtA; nxtA = tA;
    bf16_t* tB = curB; curB = nxtB; nxtB = tB;
  }

  // ----- epilogue: LDS-staged coalesced stores (verified in round 5) -----
  float* st = (float*)(&lds[0][0][0]) + wid * (16 * 68);
  const int b = m0 / S_;
  const int erow = lane >> 2;          // 0..15
  const int ecol = (lane & 3) * 16;    // 0,16,32,48
  const int gcb = n0 + wn * 64;        // wave col base
  const int qrow = (lane >> 4) * 4;
  const int qcol = lane & 15;
  f32x4 bb[4], ps[4];
#pragma unroll
  for (int q = 0; q < 4; ++q) bb[q] = *(const f32x4*)&bias[gcb + ecol + q * 4];
  if (MODE == 1) {
#pragma unroll
    for (int q = 0; q < 4; ++q) ps[q] = *(const f32x4*)&pscale[b * D_ + gcb + ecol + q * 4];
  }
#pragma unroll
  for (int m = 0; m < 8; ++m) {
#pragma unroll
    for (int n = 0; n < 4; ++n)
#pragma unroll
      for (int j = 0; j < 4; ++j)
        st[(qrow + j) * 68 + n * 16 + qcol] = acc[m][n][j];
    asm volatile("s_waitcnt lgkmcnt(0)" ::: "memory");
    __builtin_amdgcn_sched_barrier(0);
    const int grow = m0 + wm * 128 + m * 16 + erow;
    f32x4 v[4];
#pragma unroll
    for (int q = 0; q < 4; ++q) v[q] = *(f32x4*)&st[erow * 68 + ecol + q * 4];
#pragma unroll
    for (int q = 0; q < 4; ++q)
#pragma unroll
      for (int i = 0; i < 4; ++i) v[q][i] += bb[q][i];
    if (MODE == 1) {
#pragma unroll
      for (int q = 0; q < 4; ++q)
#pragma unroll
        for (int i = 0; i < 4; ++i) v[q][i] *= ps[q][i];
    }
    if (MODE == 2) {
      bf16x8 r0 = *(const bf16x8*)&resid[(size_t)grow * D_ + gcb + ecol];
      bf16x8 r1 = *(const bf16x8*)&resid[(size_t)grow * D_ + gcb + ecol + 8];
#pragma unroll
      for (int i = 0; i < 4; ++i) { v[0][i] += (float)r0[i]; v[1][i] += (float)r0[4 + i]; }
#pragma unroll
      for (int i = 0; i < 4; ++i) { v[2][i] += (float)r1[i]; v[3][i] += (float)r1[4 + i]; }
      float* op = (float*)Cout + (size_t)grow * D_ + gcb + ecol;
#pragma unroll
      for (int q = 0; q < 4; ++q) *(f32x4*)&op[q * 4] = v[q];
    } else {
      bf16x8 o0, o1;
#pragma unroll
      for (int i = 0; i < 4; ++i) { o0[i] = (bf16_t)v[0][i]; o0[4 + i] = (bf16_t)v[1][i]; }
#pragma unroll
      for (int i = 0; i < 4; ++i) { o1[i] = (bf16_t)v[2][i]; o1[4 + i] = (bf16_t)v[3][i]; }
      bf16_t* op = (bf16_t*)Cout + (size_t)grow * D_ + gcb + ecol;
      *(bf16x8*)&op[0] = o0;
      *(bf16x8*)&op[8] = o1;
    }
  }
}

// ---------------------------------------------------------------------------
// scores[b*H+h][s] = (X[b,s,:] . WaT[h,:] + ba[h]) * SCALE + mask[b][s]
// ---------------------------------------------------------------------------
__global__ __launch_bounds__(256)
void score_kernel(const bf16_t* __restrict__ X, const bf16_t* __restrict__ WaT,
                  const bf16_t* __restrict__ ba, const bf16_t* __restrict__ mask,
                  float* __restrict__ scores) {
  const int lane = threadIdx.x & 63, wid = threadIdx.x >> 6;
  const int m0 = blockIdx.x * 64 + wid * 16;
  const int ar = lane & 15, ak = (lane >> 4) * 8;
  f32x4 acc = {};
  for (int k0 = 0; k0 < D_; k0 += 32) {
    bf16x8 a = *(const bf16x8*)&X[(size_t)(m0 + ar) * D_ + k0 + ak];
    bf16x8 b = *(const bf16x8*)&WaT[(size_t)ar * D_ + k0 + ak];
    acc = __builtin_amdgcn_mfma_f32_16x16x32_bf16(a, b, acc, 0, 0, 0);
  }
  const int h = lane & 15;
  const int srow = m0 + (lane >> 4) * 4;
  const int bb = srow / S_;
  const int s0 = srow - bb * S_;
  const float bah = (float)ba[h];
  f32x4 outv;
#pragma unroll
  for (int j = 0; j < 4; ++j)
    outv[j] = (acc[j] + bah) * SCALE + (float)mask[(size_t)bb * S_ + s0 + j];
  *(f32x4*)&scores[((size_t)(bb * H_ + h)) * S_ + s0] = outv;
}

// ---------------------------------------------------------------------------
// softmax over each scores row -> normalized weights
// ---------------------------------------------------------------------------
__global__ __launch_bounds__(256)
void softmax_rows(const float* __restrict__ scores, float* __restrict__ wout) {
  __shared__ float rA[4], rB[4];
  const int tid = threadIdx.x, lane = tid & 63, wid = tid >> 6;
  const float* srow = scores + (size_t)blockIdx.x * S_;
  float* wrow = wout + (size_t)blockIdx.x * S_;
  f32x4 v0 = *(const f32x4*)&srow[tid * 4];
  f32x4 v1 = *(const f32x4*)&srow[1024 + tid * 4];
  float mx = fmaxf(fmaxf(fmaxf(v0[0], v0[1]), fmaxf(v0[2], v0[3])),
                   fmaxf(fmaxf(v1[0], v1[1]), fmaxf(v1[2], v1[3])));
#pragma unroll
  for (int o = 32; o; o >>= 1) mx = fmaxf(mx, __shfl_xor(mx, o));
  if (lane == 0) rA[wid] = mx;
  __syncthreads();
  mx = fmaxf(fmaxf(rA[0], rA[1]), fmaxf(rA[2], rA[3]));
  float sum = 0.f;
#pragma unroll
  for (int i = 0; i < 4; ++i) { v0[i] = __expf(v0[i] - mx); sum += v0[i]; }
#pragma unroll
  for (int i = 0; i < 4; ++i) { v1[i] = __expf(v1[i] - mx); sum += v1[i]; }
#pragma unroll
  for (int o = 32; o; o >>= 1) sum += __shfl_xor(sum, o);
  if (lane == 0) rB[wid] = sum;
  __syncthreads();
  sum = rB[0] + rB[1] + rB[2] + rB[3];
  const float inv = 1.0f / sum;
#pragma unroll
  for (int i = 0; i < 4; ++i) { v0[i] *= inv; v1[i] *= inv; }
  *(f32x4*)&wrow[tid * 4] = v0;
  *(f32x4*)&wrow[1024 + tid * 4] = v1;
}

// ---------------------------------------------------------------------------
// pool partials over 32-row chunks (coalesced bf16x8)
// ---------------------------------------------------------------------------
__global__ __launch_bounds__(256)
void pool_partial(const bf16_t* __restrict__ X, const float* __restrict__ w,
                  float* __restrict__ partials) {
  __shared__ float sm[2][1024];
  const int tid = threadIdx.x;
  const int chunk = blockIdx.x, b = blockIdx.y;
  const int s0 = chunk * 32;
  const int dc = (tid & 127) * 8;
  const int sp = tid >> 7;
  const int h = dc >> 6;
  const float* wrow = w + ((size_t)b * H_ + h) * S_ + s0;
  const bf16_t* Xb = X + ((size_t)b * S_ + s0) * D_ + dc;
  float acc[8] = {};
  for (int s = sp; s < 32; s += 2) {
    bf16x8 xv = *(const bf16x8*)&Xb[(size_t)s * D_];
    float wt = wrow[s];
#pragma unroll
    for (int j = 0; j < 8; ++j) acc[j] += wt * (float)xv[j];
  }
#pragma unroll
  for (int j = 0; j < 8; ++j) sm[sp][dc + j] = acc[j];
  __syncthreads();
  const int d0 = tid * 4;
  f32x4 r;
#pragma unroll
  for (int j = 0; j < 4; ++j) r[j] = sm[0][d0 + j] + sm[1][d0 + j];
  *(f32x4*)&partials[((size_t)chunk * B_ + b) * D_ + d0] = r;
}

__global__ __launch_bounds__(256)
void pool_reduce(const float* __restrict__ partials, float* __restrict__ pooled) {
  const int idx = blockIdx.x * 256 + threadIdx.x;
  float s = 0.f;
#pragma unroll 8
  for (int c = 0; c < 64; ++c) s += partials[(size_t)c * (B_ * D_) + idx];
  pooled[idx] = s;
}

// ---------------------------------------------------------------------------
// weighted[b,s,d] = mq[b,s,d] * pk[b][d]
// ---------------------------------------------------------------------------
__global__ __launch_bounds__(256)
void weighted_kernel(const bf16_t* __restrict__ mq, const float* __restrict__ pk,
                     bf16_t* __restrict__ out) {
  size_t idx = ((size_t)blockIdx.x * 256 + threadIdx.x) * 8;
  int d0 = (int)(idx & (D_ - 1));
  int b = (int)(idx >> 21);
  bf16x8 v = *(const bf16x8*)&mq[idx];
  const float* pkb = pk + (size_t)b * D_ + d0;
  bf16x8 o;
#pragma unroll
  for (int i = 0; i < 8; ++i) o[i] = (bf16_t)((float)v[i] * pkb[i]);
  *(bf16x8*)&out[idx] = o;
}

// ---------------------------------------------------------------------------
extern "C" void kernel_launch(void* const* d_in, const int* in_sizes, int n_in,
                              void* d_out, int out_size, void* d_ws, size_t ws_size,
                              hipStream_t stream) {
  const float* hs   = (const float*)d_in[0];
  const float* mask = (const float*)d_in[1];
  const float* Wq   = (const float*)d_in[2];
  const float* bq   = (const float*)d_in[3];
  const float* Wqa  = (const float*)d_in[4];
  const float* bqa  = (const float*)d_in[5];
  const float* Wk   = (const float*)d_in[6];
  const float* bk   = (const float*)d_in[7];
  const float* Wka  = (const float*)d_in[8];
  const float* bka  = (const float*)d_in[9];
  const float* Wt   = (const float*)d_in[10];
  const float* bt   = (const float*)d_in[11];

  char* ws = (char*)d_ws;
  float*  pq    = (float*)(ws + (64u << 10));
  float*  pk    = (float*)(ws + (128u << 10));
  bf16_t* bqac  = (bf16_t*)(ws + (192u << 10));
  bf16_t* bkac  = (bf16_t*)(ws + (192u << 10) + 64);
  bf16_t* maskc = (bf16_t*)(ws + (256u << 10));
  bf16_t* WqaT  = (bf16_t*)(ws + (1u << 20));
  bf16_t* WkaT  = (bf16_t*)(ws + (1u << 20) + 32768);
  bf16_t* WqT   = (bf16_t*)(ws + (2u << 20));
  bf16_t* WkT   = (bf16_t*)(ws + (4u << 20));
  bf16_t* WtT   = (bf16_t*)(ws + (6u << 20));
  bf16_t* hsb   = (bf16_t*)(ws + (8u << 20));
  bf16_t* mq    = (bf16_t*)(ws + (8u << 20) + ((size_t)64 << 20));
  bf16_t* mqk   = (bf16_t*)(ws + (8u << 20) + ((size_t)128 << 20));
  bf16_t* wtd   = (bf16_t*)(ws + (8u << 20) + ((size_t)192 << 20));
  float* scores = (float*)(ws + (8u << 20) + ((size_t)256 << 20));
  float* wsm    = (float*)(ws + (8u << 20) + ((size_t)258 << 20));
  float* parts  = (float*)(ws + (8u << 20) + ((size_t)260 << 20));

  // prep
  f32_to_bf16<<<16384, 256, 0, stream>>>(hs, hsb);
  conv_misc<<<129, 256, 0, stream>>>(bqa, bka, mask, bqac, bkac, maskc);
  transpose1024<<<dim3(16, 16), 256, 0, stream>>>(Wq, WqT);
  transpose1024<<<dim3(16, 16), 256, 0, stream>>>(Wk, WkT);
  transpose1024<<<dim3(16, 16), 256, 0, stream>>>(Wt, WtT);
  transpose_small<<<4, 256, 0, stream>>>(Wqa, WqaT);
  transpose_small<<<4, 256, 0, stream>>>(Wka, WkaT);

  // mixed_q = hs @ Wq + bq
  gemm256<0><<<512, 512, 0, stream>>>(hsb, WqT, bq, mq, nullptr, nullptr);

  score_kernel<<<512, 256, 0, stream>>>(mq, WqaT, bqac, maskc, scores);
  softmax_rows<<<256, 256, 0, stream>>>(scores, wsm);
  pool_partial<<<dim3(64, 16), 256, 0, stream>>>(mq, wsm, parts);
  pool_reduce<<<64, 256, 0, stream>>>(parts, pq);

  // mixed_qk = (hs @ Wk + bk) * pooled_q
  gemm256<1><<<512, 512, 0, stream>>>(hsb, WkT, bk, mqk, pq, nullptr);

  score_kernel<<<512, 256, 0, stream>>>(mqk, WkaT, bkac, maskc, scores);
  softmax_rows<<<256, 256, 0, stream>>>(scores, wsm);
  pool_partial<<<dim3(64, 16), 256, 0, stream>>>(mqk, wsm, parts);
  pool_reduce<<<64, 256, 0, stream>>>(parts, pk);

  // weighted = mq * pooled_k
  weighted_kernel<<<16384, 256, 0, stream>>>(mq, pk, wtd);

  // out = weighted @ Wt + bt + mixed_q   (f32 out)
  gemm256<2><<<512, 512, 0, stream>>>(wtd, WtT, bt, d_out, nullptr, mq);
}

// Round 7
// 398.153 us; speedup vs baseline: 1.9001x; 1.0373x over previous
//
#include <hip/hip_runtime.h>
#include <hip/hip_bf16.h>
#include <stdint.h>

#define D_ 1024
#define H_ 16
#define DH_ 64
#define S_ 2048
#define B_ 16
static constexpr float SCALE = 0.125f;  // 1/sqrt(64)

typedef __bf16 bf16_t;
typedef __bf16 bf16x8 __attribute__((ext_vector_type(8)));
typedef __bf16 bf16x4 __attribute__((ext_vector_type(4)));
typedef float  f32x4  __attribute__((ext_vector_type(4)));

__device__ __forceinline__ void llds16(const void* g, void* l) {
  __builtin_amdgcn_global_load_lds(
      (const __attribute__((address_space(1))) void*)g,
      (__attribute__((address_space(3))) void*)l, 16, 0, 0);
}

// ---------------------------------------------------------------------------
// hidden_states f32 -> bf16
// ---------------------------------------------------------------------------
__global__ __launch_bounds__(256)
void f32_to_bf16(const float* __restrict__ src, bf16_t* __restrict__ dst) {
  size_t base = ((size_t)blockIdx.x * 256 + threadIdx.x) * 8;
  f32x4 a = *(const f32x4*)&src[base];
  f32x4 b = *(const f32x4*)&src[base + 4];
  bf16x8 o;
#pragma unroll
  for (int i = 0; i < 4; ++i) { o[i] = (bf16_t)a[i]; o[4 + i] = (bf16_t)b[i]; }
  *(bf16x8*)&dst[base] = o;
}

// ---------------------------------------------------------------------------
// 1024x1024 f32 -> bf16 transpose: dst[n][k] = src[k][n]
// ---------------------------------------------------------------------------
__global__ __launch_bounds__(256)
void transpose1024(const float* __restrict__ src, bf16_t* __restrict__ dst) {
  __shared__ bf16_t t[64][65];
  const int n0 = blockIdx.x * 64, k0 = blockIdx.y * 64;
  const int r = threadIdx.x >> 4, c4 = (threadIdx.x & 15) * 4;
#pragma unroll
  for (int p = 0; p < 4; ++p) {
    int row = p * 16 + r;
    f32x4 f = *(const f32x4*)&src[(size_t)(k0 + row) * 1024 + n0 + c4];
#pragma unroll
    for (int i = 0; i < 4; ++i) t[row][c4 + i] = (bf16_t)f[i];
  }
  __syncthreads();
#pragma unroll
  for (int p = 0; p < 4; ++p) {
    int row = p * 16 + r;
    bf16x4 v;
#pragma unroll
    for (int i = 0; i < 4; ++i) v[i] = t[c4 + i][row];
    *(bf16x4*)&dst[(size_t)(n0 + row) * 1024 + k0 + c4] = v;
  }
}

// [1024][16] f32 -> [16][1024] bf16
__global__ __launch_bounds__(256)
void transpose_small(const float* __restrict__ src, bf16_t* __restrict__ dst) {
  int k = blockIdx.x * 256 + threadIdx.x;
  if (k < 1024) {
#pragma unroll
    for (int h = 0; h < H_; ++h) dst[h * 1024 + k] = (bf16_t)src[k * H_ + h];
  }
}

// small biases + mask f32 -> bf16 (for score kernels)
__global__ __launch_bounds__(256)
void conv_misc(const float* bqa, const float* bka, const float* mask,
               bf16_t* obqa, bf16_t* obka, bf16_t* omask) {
  int i = blockIdx.x * 256 + threadIdx.x;
  const float* src; bf16_t* dst; int off;
  if      (i < 16)    { src = bqa;  dst = obqa;  off = i; }
  else if (i < 32)    { src = bka;  dst = obka;  off = i - 16; }
  else if (i < 32800) { src = mask; dst = omask; off = i - 32; }
  else return;
  dst[off] = (bf16_t)src[off];
}

// ---------------------------------------------------------------------------
// 256x256-tile GEMM, BK=64, 8 waves (2x4), LDS double-buffer (128 KiB).
// Counted-vmcnt pipeline: per K-tile {issue 8 loads (t+1 -> nxt);
// s_waitcnt vmcnt(8) [tile t landed, t+1 stays in flight]; barrier;
// 2 half-K phases of fragment-once ds_reads (12) + setprio 32-MFMA cluster;
// barrier; swap}. vmcnt never drains to 0 in the main loop (T4).
// T2 involution swizzle on staging/reads (measured 0 conflicts).
// MODE 0: -> bf16 (mixed_q); MODE 1: *pscale -> bf16 (mixed_qk);
// MODE 2: +resid -> f32 (final output)
// ---------------------------------------------------------------------------
template <int MODE>
__global__ __launch_bounds__(512, 1)
void gemm256(const bf16_t* __restrict__ A, const bf16_t* __restrict__ BT,
             const float* __restrict__ bias, void* __restrict__ Cout,
             const float* __restrict__ pscale, const bf16_t* __restrict__ resid) {
  constexpr int K = 1024;
  __shared__ __align__(16) bf16_t lds[2][2][256 * 64];
  const int tid = threadIdx.x;
  const int lane = tid & 63, wid = tid >> 6;   // 8 waves
  const int wm = wid >> 2, wn = wid & 3;       // 2 x 4 wave grid

  // XCD swizzle: nwg=512, 512%8==0 -> 64 contiguous ids per XCD
  const int wgid = (blockIdx.x & 7) * 64 + (blockIdx.x >> 3);
  const int m0 = (wgid >> 2) * 256;
  const int n0 = (wgid & 3) * 256;

  // staging: 4 chunks/thread/matrix; chunk c -> row c>>3, slot c&7;
  // slot j holds global col-chunk j^(row&7)  (T2 involution)
  const bf16_t* gA[4];
  const bf16_t* gB[4];
  int ldsOff[4];
#pragma unroll
  for (int i = 0; i < 4; ++i) {
    int c = i * 512 + tid;
    int r = c >> 3, j = c & 7;
    int col = ((j ^ (r & 7)) << 3);
    gA[i] = A  + (size_t)(m0 + r) * K + col;
    gB[i] = BT + (size_t)(n0 + r) * K + col;
    ldsOff[i] = c * 8;
  }

  f32x4 acc[8][4] = {};
  const int ar = lane & 15;
  const int kq = lane >> 4;  // 16B k-chunk within 32-k-step

  bf16_t* curA = &lds[0][0][0]; bf16_t* curB = &lds[0][1][0];
  bf16_t* nxtA = &lds[1][0][0]; bf16_t* nxtB = &lds[1][1][0];

  // prologue: stage K-tile 0
#pragma unroll
  for (int i = 0; i < 4; ++i) { llds16(gA[i], curA + ldsOff[i]); llds16(gB[i], curB + ldsOff[i]); }

  for (int t = 0; t < 16; ++t) {
    if (t < 15) {  // stage tile t+1 into the buffer NOT being read
      const int koff = (t + 1) * 64;
#pragma unroll
      for (int i = 0; i < 4; ++i) {
        llds16(gA[i] + koff, nxtA + ldsOff[i]);
        llds16(gB[i] + koff, nxtB + ldsOff[i]);
      }
      asm volatile("s_waitcnt vmcnt(8)" ::: "memory");  // tile t landed
    } else {
      asm volatile("s_waitcnt vmcnt(0)" ::: "memory");
    }
    __builtin_amdgcn_s_barrier();

#pragma unroll
    for (int h = 0; h < 2; ++h) {
      bf16x8 af[8], bg[4];
#pragma unroll
      for (int m = 0; m < 8; ++m) {
        int r = wm * 128 + m * 16 + ar;
        af[m] = *(const bf16x8*)&curA[r * 64 + (((h * 4 + kq) ^ (r & 7)) << 3)];
      }
#pragma unroll
      for (int n = 0; n < 4; ++n) {
        int r = wn * 64 + n * 16 + ar;
        bg[n] = *(const bf16x8*)&curB[r * 64 + (((h * 4 + kq) ^ (r & 7)) << 3)];
      }
      __builtin_amdgcn_s_setprio(1);
#pragma unroll
      for (int m = 0; m < 8; ++m)
#pragma unroll
        for (int n = 0; n < 4; ++n)
          acc[m][n] = __builtin_amdgcn_mfma_f32_16x16x32_bf16(af[m], bg[n], acc[m][n], 0, 0, 0);
      __builtin_amdgcn_s_setprio(0);
    }
    __builtin_amdgcn_s_barrier();  // all reads of cur consumed -> safe to overwrite next tile
    bf16_t* tA = curA; curA = nxtA; nxtA = tA;
    bf16_t* tB = curB; curB = nxtB; nxtB = tB;
  }

  // ----- epilogue: LDS-staged coalesced stores (refcheck'd r5/r6) -----
  float* st = (float*)(&lds[0][0][0]) + wid * (16 * 68);
  const int b = m0 / S_;
  const int erow = lane >> 2;          // 0..15
  const int ecol = (lane & 3) * 16;    // 0,16,32,48
  const int gcb = n0 + wn * 64;        // wave col base
  const int qrow = (lane >> 4) * 4;
  const int qcol = lane & 15;
  f32x4 bb[4], ps[4];
#pragma unroll
  for (int q = 0; q < 4; ++q) bb[q] = *(const f32x4*)&bias[gcb + ecol + q * 4];
  if (MODE == 1) {
#pragma unroll
    for (int q = 0; q < 4; ++q) ps[q] = *(const f32x4*)&pscale[b * D_ + gcb + ecol + q * 4];
  }
#pragma unroll
  for (int m = 0; m < 8; ++m) {
#pragma unroll
    for (int n = 0; n < 4; ++n)
#pragma unroll
      for (int j = 0; j < 4; ++j)
        st[(qrow + j) * 68 + n * 16 + qcol] = acc[m][n][j];
    asm volatile("s_waitcnt lgkmcnt(0)" ::: "memory");
    __builtin_amdgcn_sched_barrier(0);
    const int grow = m0 + wm * 128 + m * 16 + erow;
    f32x4 v[4];
#pragma unroll
    for (int q = 0; q < 4; ++q) v[q] = *(f32x4*)&st[erow * 68 + ecol + q * 4];
#pragma unroll
    for (int q = 0; q < 4; ++q)
#pragma unroll
      for (int i = 0; i < 4; ++i) v[q][i] += bb[q][i];
    if (MODE == 1) {
#pragma unroll
      for (int q = 0; q < 4; ++q)
#pragma unroll
        for (int i = 0; i < 4; ++i) v[q][i] *= ps[q][i];
    }
    if (MODE == 2) {
      bf16x8 r0 = *(const bf16x8*)&resid[(size_t)grow * D_ + gcb + ecol];
      bf16x8 r1 = *(const bf16x8*)&resid[(size_t)grow * D_ + gcb + ecol + 8];
#pragma unroll
      for (int i = 0; i < 4; ++i) { v[0][i] += (float)r0[i]; v[1][i] += (float)r0[4 + i]; }
#pragma unroll
      for (int i = 0; i < 4; ++i) { v[2][i] += (float)r1[i]; v[3][i] += (float)r1[4 + i]; }
      float* op = (float*)Cout + (size_t)grow * D_ + gcb + ecol;
#pragma unroll
      for (int q = 0; q < 4; ++q) *(f32x4*)&op[q * 4] = v[q];
    } else {
      bf16x8 o0, o1;
#pragma unroll
      for (int i = 0; i < 4; ++i) { o0[i] = (bf16_t)v[0][i]; o0[4 + i] = (bf16_t)v[1][i]; }
#pragma unroll
      for (int i = 0; i < 4; ++i) { o1[i] = (bf16_t)v[2][i]; o1[4 + i] = (bf16_t)v[3][i]; }
      bf16_t* op = (bf16_t*)Cout + (size_t)grow * D_ + gcb + ecol;
      *(bf16x8*)&op[0] = o0;
      *(bf16x8*)&op[8] = o1;
    }
  }
}

// ---------------------------------------------------------------------------
// scores[b*H+h][s] = (X[b,s,:] . WaT[h,:] + ba[h]) * SCALE + mask[b][s]
// ---------------------------------------------------------------------------
__global__ __launch_bounds__(256)
void score_kernel(const bf16_t* __restrict__ X, const bf16_t* __restrict__ WaT,
                  const bf16_t* __restrict__ ba, const bf16_t* __restrict__ mask,
                  float* __restrict__ scores) {
  const int lane = threadIdx.x & 63, wid = threadIdx.x >> 6;
  const int m0 = blockIdx.x * 64 + wid * 16;
  const int ar = lane & 15, ak = (lane >> 4) * 8;
  f32x4 acc = {};
  for (int k0 = 0; k0 < D_; k0 += 32) {
    bf16x8 a = *(const bf16x8*)&X[(size_t)(m0 + ar) * D_ + k0 + ak];
    bf16x8 b = *(const bf16x8*)&WaT[(size_t)ar * D_ + k0 + ak];
    acc = __builtin_amdgcn_mfma_f32_16x16x32_bf16(a, b, acc, 0, 0, 0);
  }
  const int h = lane & 15;
  const int srow = m0 + (lane >> 4) * 4;
  const int bb = srow / S_;
  const int s0 = srow - bb * S_;
  const float bah = (float)ba[h];
  f32x4 outv;
#pragma unroll
  for (int j = 0; j < 4; ++j)
    outv[j] = (acc[j] + bah) * SCALE + (float)mask[(size_t)bb * S_ + s0 + j];
  *(f32x4*)&scores[((size_t)(bb * H_ + h)) * S_ + s0] = outv;
}

// ---------------------------------------------------------------------------
// softmax over each scores row -> normalized weights
// ---------------------------------------------------------------------------
__global__ __launch_bounds__(256)
void softmax_rows(const float* __restrict__ scores, float* __restrict__ wout) {
  __shared__ float rA[4], rB[4];
  const int tid = threadIdx.x, lane = tid & 63, wid = tid >> 6;
  const float* srow = scores + (size_t)blockIdx.x * S_;
  float* wrow = wout + (size_t)blockIdx.x * S_;
  f32x4 v0 = *(const f32x4*)&srow[tid * 4];
  f32x4 v1 = *(const f32x4*)&srow[1024 + tid * 4];
  float mx = fmaxf(fmaxf(fmaxf(v0[0], v0[1]), fmaxf(v0[2], v0[3])),
                   fmaxf(fmaxf(v1[0], v1[1]), fmaxf(v1[2], v1[3])));
#pragma unroll
  for (int o = 32; o; o >>= 1) mx = fmaxf(mx, __shfl_xor(mx, o));
  if (lane == 0) rA[wid] = mx;
  __syncthreads();
  mx = fmaxf(fmaxf(rA[0], rA[1]), fmaxf(rA[2], rA[3]));
  float sum = 0.f;
#pragma unroll
  for (int i = 0; i < 4; ++i) { v0[i] = __expf(v0[i] - mx); sum += v0[i]; }
#pragma unroll
  for (int i = 0; i < 4; ++i) { v1[i] = __expf(v1[i] - mx); sum += v1[i]; }
#pragma unroll
  for (int o = 32; o; o >>= 1) sum += __shfl_xor(sum, o);
  if (lane == 0) rB[wid] = sum;
  __syncthreads();
  sum = rB[0] + rB[1] + rB[2] + rB[3];
  const float inv = 1.0f / sum;
#pragma unroll
  for (int i = 0; i < 4; ++i) { v0[i] *= inv; v1[i] *= inv; }
  *(f32x4*)&wrow[tid * 4] = v0;
  *(f32x4*)&wrow[1024 + tid * 4] = v1;
}

// ---------------------------------------------------------------------------
// pool partials over 32-row chunks (coalesced bf16x8)
// ---------------------------------------------------------------------------
__global__ __launch_bounds__(256)
void pool_partial(const bf16_t* __restrict__ X, const float* __restrict__ w,
                  float* __restrict__ partials) {
  __shared__ float sm[2][1024];
  const int tid = threadIdx.x;
  const int chunk = blockIdx.x, b = blockIdx.y;
  const int s0 = chunk * 32;
  const int dc = (tid & 127) * 8;
  const int sp = tid >> 7;
  const int h = dc >> 6;
  const float* wrow = w + ((size_t)b * H_ + h) * S_ + s0;
  const bf16_t* Xb = X + ((size_t)b * S_ + s0) * D_ + dc;
  float acc[8] = {};
  for (int s = sp; s < 32; s += 2) {
    bf16x8 xv = *(const bf16x8*)&Xb[(size_t)s * D_];
    float wt = wrow[s];
#pragma unroll
    for (int j = 0; j < 8; ++j) acc[j] += wt * (float)xv[j];
  }
#pragma unroll
  for (int j = 0; j < 8; ++j) sm[sp][dc + j] = acc[j];
  __syncthreads();
  const int d0 = tid * 4;
  f32x4 r;
#pragma unroll
  for (int j = 0; j < 4; ++j) r[j] = sm[0][d0 + j] + sm[1][d0 + j];
  *(f32x4*)&partials[((size_t)chunk * B_ + b) * D_ + d0] = r;
}

__global__ __launch_bounds__(256)
void pool_reduce(const float* __restrict__ partials, float* __restrict__ pooled) {
  const int idx = blockIdx.x * 256 + threadIdx.x;
  float s = 0.f;
#pragma unroll 8
  for (int c = 0; c < 64; ++c) s += partials[(size_t)c * (B_ * D_) + idx];
  pooled[idx] = s;
}

// ---------------------------------------------------------------------------
// weighted[b,s,d] = mq[b,s,d] * pk[b][d]
// ---------------------------------------------------------------------------
__global__ __launch_bounds__(256)
void weighted_kernel(const bf16_t* __restrict__ mq, const float* __restrict__ pk,
                     bf16_t* __restrict__ out) {
  size_t idx = ((size_t)blockIdx.x * 256 + threadIdx.x) * 8;
  int d0 = (int)(idx & (D_ - 1));
  int b = (int)(idx >> 21);
  bf16x8 v = *(const bf16x8*)&mq[idx];
  const float* pkb = pk + (size_t)b * D_ + d0;
  bf16x8 o;
#pragma unroll
  for (int i = 0; i < 8; ++i) o[i] = (bf16_t)((float)v[i] * pkb[i]);
  *(bf16x8*)&out[idx] = o;
}

// ---------------------------------------------------------------------------
extern "C" void kernel_launch(void* const* d_in, const int* in_sizes, int n_in,
                              void* d_out, int out_size, void* d_ws, size_t ws_size,
                              hipStream_t stream) {
  const float* hs   = (const float*)d_in[0];
  const float* mask = (const float*)d_in[1];
  const float* Wq   = (const float*)d_in[2];
  const float* bq   = (const float*)d_in[3];
  const float* Wqa  = (const float*)d_in[4];
  const float* bqa  = (const float*)d_in[5];
  const float* Wk   = (const float*)d_in[6];
  const float* bk   = (const float*)d_in[7];
  const float* Wka  = (const float*)d_in[8];
  const float* bka  = (const float*)d_in[9];
  const float* Wt   = (const float*)d_in[10];
  const float* bt   = (const float*)d_in[11];

  char* ws = (char*)d_ws;
  float*  pq    = (float*)(ws + (64u << 10));
  float*  pk    = (float*)(ws + (128u << 10));
  bf16_t* bqac  = (bf16_t*)(ws + (192u << 10));
  bf16_t* bkac  = (bf16_t*)(ws + (192u << 10) + 64);
  bf16_t* maskc = (bf16_t*)(ws + (256u << 10));
  bf16_t* WqaT  = (bf16_t*)(ws + (1u << 20));
  bf16_t* WkaT  = (bf16_t*)(ws + (1u << 20) + 32768);
  bf16_t* WqT   = (bf16_t*)(ws + (2u << 20));
  bf16_t* WkT   = (bf16_t*)(ws + (4u << 20));
  bf16_t* WtT   = (bf16_t*)(ws + (6u << 20));
  bf16_t* hsb   = (bf16_t*)(ws + (8u << 20));
  bf16_t* mq    = (bf16_t*)(ws + (8u << 20) + ((size_t)64 << 20));
  bf16_t* mqk   = (bf16_t*)(ws + (8u << 20) + ((size_t)128 << 20));
  bf16_t* wtd   = (bf16_t*)(ws + (8u << 20) + ((size_t)192 << 20));
  float* scores = (float*)(ws + (8u << 20) + ((size_t)256 << 20));
  float* wsm    = (float*)(ws + (8u << 20) + ((size_t)258 << 20));
  float* parts  = (float*)(ws + (8u << 20) + ((size_t)260 << 20));

  // prep
  f32_to_bf16<<<16384, 256, 0, stream>>>(hs, hsb);
  conv_misc<<<129, 256, 0, stream>>>(bqa, bka, mask, bqac, bkac, maskc);
  transpose1024<<<dim3(16, 16), 256, 0, stream>>>(Wq, WqT);
  transpose1024<<<dim3(16, 16), 256, 0, stream>>>(Wk, WkT);
  transpose1024<<<dim3(16, 16), 256, 0, stream>>>(Wt, WtT);
  transpose_small<<<4, 256, 0, stream>>>(Wqa, WqaT);
  transpose_small<<<4, 256, 0, stream>>>(Wka, WkaT);

  // mixed_q = hs @ Wq + bq
  gemm256<0><<<512, 512, 0, stream>>>(hsb, WqT, bq, mq, nullptr, nullptr);

  score_kernel<<<512, 256, 0, stream>>>(mq, WqaT, bqac, maskc, scores);
  softmax_rows<<<256, 256, 0, stream>>>(scores, wsm);
  pool_partial<<<dim3(64, 16), 256, 0, stream>>>(mq, wsm, parts);
  pool_reduce<<<64, 256, 0, stream>>>(parts, pq);

  // mixed_qk = (hs @ Wk + bk) * pooled_q
  gemm256<1><<<512, 512, 0, stream>>>(hsb, WkT, bk, mqk, pq, nullptr);

  score_kernel<<<512, 256, 0, stream>>>(mqk, WkaT, bkac, maskc, scores);
  softmax_rows<<<256, 256, 0, stream>>>(scores, wsm);
  pool_partial<<<dim3(64, 16), 256, 0, stream>>>(mqk, wsm, parts);
  pool_reduce<<<64, 256, 0, stream>>>(parts, pk);

  // weighted = mq * pooled_k
  weighted_kernel<<<16384, 256, 0, stream>>>(mq, pk, wtd);

  // out = weighted @ Wt + bt + mixed_q   (f32 out)
  gemm256<2><<<512, 512, 0, stream>>>(wtd, WtT, bt, d_out, nullptr, mq);
}

// Round 8
// 394.023 us; speedup vs baseline: 1.9200x; 1.0105x over previous
//
#include <hip/hip_runtime.h>
#include <hip/hip_bf16.h>
#include <stdint.h>

#define D_ 1024
#define H_ 16
#define DH_ 64
#define S_ 2048
#define B_ 16
static constexpr float SCALE = 0.125f;  // 1/sqrt(64)

typedef __bf16 bf16_t;
typedef __bf16 bf16x8 __attribute__((ext_vector_type(8)));
typedef __bf16 bf16x4 __attribute__((ext_vector_type(4)));
typedef float  f32x4  __attribute__((ext_vector_type(4)));

__device__ __forceinline__ void llds16(const void* g, void* l) {
  __builtin_amdgcn_global_load_lds(
      (const __attribute__((address_space(1))) void*)g,
      (__attribute__((address_space(3))) void*)l, 16, 0, 0);
}

// ---------------------------------------------------------------------------
// hidden_states f32 -> bf16
// ---------------------------------------------------------------------------
__global__ __launch_bounds__(256)
void f32_to_bf16(const float* __restrict__ src, bf16_t* __restrict__ dst) {
  size_t base = ((size_t)blockIdx.x * 256 + threadIdx.x) * 8;
  f32x4 a = *(const f32x4*)&src[base];
  f32x4 b = *(const f32x4*)&src[base + 4];
  bf16x8 o;
#pragma unroll
  for (int i = 0; i < 4; ++i) { o[i] = (bf16_t)a[i]; o[4 + i] = (bf16_t)b[i]; }
  *(bf16x8*)&dst[base] = o;
}

// ---------------------------------------------------------------------------
// 3x 1024x1024 f32 -> bf16 transpose in one launch: dst[n][k] = src[k][n]
// ---------------------------------------------------------------------------
__global__ __launch_bounds__(256)
void transpose1024_all(const float* __restrict__ s0, const float* __restrict__ s1,
                       const float* __restrict__ s2, bf16_t* __restrict__ d0,
                       bf16_t* __restrict__ d1, bf16_t* __restrict__ d2) {
  __shared__ bf16_t t[64][65];
  const float* src = (blockIdx.z == 0) ? s0 : (blockIdx.z == 1) ? s1 : s2;
  bf16_t* dst      = (blockIdx.z == 0) ? d0 : (blockIdx.z == 1) ? d1 : d2;
  const int n0 = blockIdx.x * 64, k0 = blockIdx.y * 64;
  const int r = threadIdx.x >> 4, c4 = (threadIdx.x & 15) * 4;
#pragma unroll
  for (int p = 0; p < 4; ++p) {
    int row = p * 16 + r;
    f32x4 f = *(const f32x4*)&src[(size_t)(k0 + row) * 1024 + n0 + c4];
#pragma unroll
    for (int i = 0; i < 4; ++i) t[row][c4 + i] = (bf16_t)f[i];
  }
  __syncthreads();
#pragma unroll
  for (int p = 0; p < 4; ++p) {
    int row = p * 16 + r;
    bf16x4 v;
#pragma unroll
    for (int i = 0; i < 4; ++i) v[i] = t[c4 + i][row];
    *(bf16x4*)&dst[(size_t)(n0 + row) * 1024 + k0 + c4] = v;
  }
}

// [1024][16] f32 -> [16][1024] bf16, both Wqa and Wka in one launch
__global__ __launch_bounds__(256)
void transpose_small_all(const float* __restrict__ sa, const float* __restrict__ sb,
                         bf16_t* __restrict__ da, bf16_t* __restrict__ db) {
  int g = blockIdx.x * 256 + threadIdx.x;
  const float* src = (g < 1024) ? sa : sb;
  bf16_t* dst      = (g < 1024) ? da : db;
  int k = g & 1023;
#pragma unroll
  for (int h = 0; h < H_; ++h) dst[h * 1024 + k] = (bf16_t)src[k * H_ + h];
}

// small biases + mask f32 -> bf16 (for score kernels)
__global__ __launch_bounds__(256)
void conv_misc(const float* bqa, const float* bka, const float* mask,
               bf16_t* obqa, bf16_t* obka, bf16_t* omask) {
  int i = blockIdx.x * 256 + threadIdx.x;
  const float* src; bf16_t* dst; int off;
  if      (i < 16)    { src = bqa;  dst = obqa;  off = i; }
  else if (i < 32)    { src = bka;  dst = obka;  off = i - 16; }
  else if (i < 32800) { src = mask; dst = omask; off = i - 32; }
  else return;
  dst[off] = (bf16_t)src[off];
}

// ---------------------------------------------------------------------------
// GEMM: C[M][1024] = A[M][1024] @ BT[1024][1024]^T + bias (+epilogue)
// m97 128x128 structure (round-4 measured-best) + slot-rotation LDS swizzle
// (2-way = free reads; was 8-way/8.4M conflicts) + LDS-staged coalesced
// epilogue (fixes 2x write amplification).
// LDS layout: row r (64B = 4 slots of 16B); slot s holds global k-chunk
// (s - (r>>1)) & 3. Staging keeps the linear gload_lds dest and pre-swizzles
// the global source col; reads rotate: chunk kq -> slot (kq + (r>>1)) & 3.
// MODE 0: -> bf16 (mixed_q)
// MODE 1: *pscale[b][col] -> bf16 (mixed_qk)
// MODE 2: A-staging fused with pkA[b][k] (weighted = mq*pk), +resid -> f32
// ---------------------------------------------------------------------------
template <int MODE>
__global__ __launch_bounds__(256, 2)
void gemm_bt(const bf16_t* __restrict__ A, const bf16_t* __restrict__ BT,
             const float* __restrict__ bias, void* __restrict__ Cout,
             const float* __restrict__ pscale, const bf16_t* __restrict__ resid,
             const float* __restrict__ pkA) {
  constexpr int K = 1024, N = 1024;
  __shared__ __align__(16) bf16_t lA[128 * 32];
  __shared__ __align__(16) bf16_t lB[128 * 32];
  __shared__ __align__(16) float est[4][16 * 68];
  const int tid = threadIdx.x;
  const int lane = tid & 63, wid = tid >> 6;
  const int wr = wid >> 1, wc = wid & 1;

  // XCD swizzle: nwg=2048, 2048%8==0
  const int wgid = (blockIdx.x & 7) * 256 + (blockIdx.x >> 3);
  const int m0 = (wgid >> 3) * 128;
  const int n0 = (wgid & 7) * 128;
  const int b = m0 / S_;

  const int ar = lane & 15;
  const int kq = lane >> 4;   // k-chunk 0..3 within the 32-k tile

  // staging chunk map (2 chunks per thread per matrix)
  int rowc[2], colc[2], dstoff[2];
#pragma unroll
  for (int j = 0; j < 2; ++j) {
    int c = j * 256 + tid;          // 0..511
    int row = c >> 2, s = c & 3;    // lds row, lds slot
    rowc[j] = row;
    colc[j] = (((s - (row >> 1)) & 3) << 3);  // global k-chunk for this slot
    dstoff[j] = c * 8;              // linear lds dest (elements)
  }

  f32x4 acc[4][4] = {};

  for (int k0 = 0; k0 < K; k0 += 32) {
#pragma unroll
    for (int j = 0; j < 2; ++j) {
      const bf16_t* gb = BT + (size_t)(n0 + rowc[j]) * K + k0 + colc[j];
      llds16(gb, lB + dstoff[j]);
      if (MODE == 2) {
        // fused weighted: A-chunk = mq * pk[b][k], reg-staged
        bf16x8 v = *(const bf16x8*)(A + (size_t)(m0 + rowc[j]) * K + k0 + colc[j]);
        const float* pkp = pkA + b * D_ + k0 + colc[j];
        f32x4 p0 = *(const f32x4*)pkp;
        f32x4 p1 = *(const f32x4*)(pkp + 4);
        bf16x8 o;
#pragma unroll
        for (int i = 0; i < 4; ++i) {
          o[i]     = (bf16_t)((float)v[i] * p0[i]);
          o[4 + i] = (bf16_t)((float)v[4 + i] * p1[i]);
        }
        *(bf16x8*)&lA[dstoff[j]] = o;
      } else {
        const bf16_t* ga = A + (size_t)(m0 + rowc[j]) * K + k0 + colc[j];
        llds16(ga, lA + dstoff[j]);
      }
    }
    __syncthreads();
    bf16x8 af[4], bg[4];
#pragma unroll
    for (int m = 0; m < 4; ++m) {
      int r = wr * 64 + m * 16 + ar;
      af[m] = *(const bf16x8*)&lA[r * 32 + (((kq + (r >> 1)) & 3) << 3)];
    }
#pragma unroll
    for (int n = 0; n < 4; ++n) {
      int r = wc * 64 + n * 16 + ar;
      bg[n] = *(const bf16x8*)&lB[r * 32 + (((kq + (r >> 1)) & 3) << 3)];
    }
#pragma unroll
    for (int m = 0; m < 4; ++m)
#pragma unroll
      for (int n = 0; n < 4; ++n)
        acc[m][n] = __builtin_amdgcn_mfma_f32_16x16x32_bf16(af[m], bg[n], acc[m][n], 0, 0, 0);
    __syncthreads();
  }

  // ----- epilogue: LDS-staged coalesced stores (refcheck'd r5-r7) -----
  float* st = est[wid];
  const int erow = lane >> 2;          // 0..15
  const int ecol = (lane & 3) * 16;    // 0,16,32,48
  const int gcb = n0 + wc * 64;        // wave col base
  const int qrow = (lane >> 4) * 4;
  const int qcol = lane & 15;
  f32x4 bb[4], ps[4];
#pragma unroll
  for (int q = 0; q < 4; ++q) bb[q] = *(const f32x4*)&bias[gcb + ecol + q * 4];
  if (MODE == 1) {
#pragma unroll
    for (int q = 0; q < 4; ++q) ps[q] = *(const f32x4*)&pscale[b * D_ + gcb + ecol + q * 4];
  }
#pragma unroll
  for (int m = 0; m < 4; ++m) {
#pragma unroll
    for (int n = 0; n < 4; ++n)
#pragma unroll
      for (int j = 0; j < 4; ++j)
        st[(qrow + j) * 68 + n * 16 + qcol] = acc[m][n][j];
    asm volatile("s_waitcnt lgkmcnt(0)" ::: "memory");
    __builtin_amdgcn_sched_barrier(0);
    const int grow = m0 + wr * 64 + m * 16 + erow;
    f32x4 v[4];
#pragma unroll
    for (int q = 0; q < 4; ++q) v[q] = *(f32x4*)&st[erow * 68 + ecol + q * 4];
#pragma unroll
    for (int q = 0; q < 4; ++q)
#pragma unroll
      for (int i = 0; i < 4; ++i) v[q][i] += bb[q][i];
    if (MODE == 1) {
#pragma unroll
      for (int q = 0; q < 4; ++q)
#pragma unroll
        for (int i = 0; i < 4; ++i) v[q][i] *= ps[q][i];
    }
    if (MODE == 2) {
      bf16x8 r0 = *(const bf16x8*)&resid[(size_t)grow * N + gcb + ecol];
      bf16x8 r1 = *(const bf16x8*)&resid[(size_t)grow * N + gcb + ecol + 8];
#pragma unroll
      for (int i = 0; i < 4; ++i) { v[0][i] += (float)r0[i]; v[1][i] += (float)r0[4 + i]; }
#pragma unroll
      for (int i = 0; i < 4; ++i) { v[2][i] += (float)r1[i]; v[3][i] += (float)r1[4 + i]; }
      float* op = (float*)Cout + (size_t)grow * N + gcb + ecol;
#pragma unroll
      for (int q = 0; q < 4; ++q) *(f32x4*)&op[q * 4] = v[q];
    } else {
      bf16x8 o0, o1;
#pragma unroll
      for (int i = 0; i < 4; ++i) { o0[i] = (bf16_t)v[0][i]; o0[4 + i] = (bf16_t)v[1][i]; }
#pragma unroll
      for (int i = 0; i < 4; ++i) { o1[i] = (bf16_t)v[2][i]; o1[4 + i] = (bf16_t)v[3][i]; }
      bf16_t* op = (bf16_t*)Cout + (size_t)grow * N + gcb + ecol;
      *(bf16x8*)&op[0] = o0;
      *(bf16x8*)&op[8] = o1;
    }
    // est slice is wave-private; within-wave lgkmcnt orders next m's overwrite
  }
}

// ---------------------------------------------------------------------------
// scores[b*H+h][s] = (X[b,s,:] . WaT[h,:] + ba[h]) * SCALE + mask[b][s]
// ---------------------------------------------------------------------------
__global__ __launch_bounds__(256)
void score_kernel(const bf16_t* __restrict__ X, const bf16_t* __restrict__ WaT,
                  const bf16_t* __restrict__ ba, const bf16_t* __restrict__ mask,
                  float* __restrict__ scores) {
  const int lane = threadIdx.x & 63, wid = threadIdx.x >> 6;
  const int m0 = blockIdx.x * 64 + wid * 16;
  const int ar = lane & 15, ak = (lane >> 4) * 8;
  f32x4 acc = {};
  for (int k0 = 0; k0 < D_; k0 += 32) {
    bf16x8 a = *(const bf16x8*)&X[(size_t)(m0 + ar) * D_ + k0 + ak];
    bf16x8 b = *(const bf16x8*)&WaT[(size_t)ar * D_ + k0 + ak];
    acc = __builtin_amdgcn_mfma_f32_16x16x32_bf16(a, b, acc, 0, 0, 0);
  }
  const int h = lane & 15;
  const int srow = m0 + (lane >> 4) * 4;
  const int bb = srow / S_;
  const int s0 = srow - bb * S_;
  const float bah = (float)ba[h];
  f32x4 outv;
#pragma unroll
  for (int j = 0; j < 4; ++j)
    outv[j] = (acc[j] + bah) * SCALE + (float)mask[(size_t)bb * S_ + s0 + j];
  *(f32x4*)&scores[((size_t)(bb * H_ + h)) * S_ + s0] = outv;
}

// ---------------------------------------------------------------------------
// softmax over each scores row -> normalized weights
// ---------------------------------------------------------------------------
__global__ __launch_bounds__(256)
void softmax_rows(const float* __restrict__ scores, float* __restrict__ wout) {
  __shared__ float rA[4], rB[4];
  const int tid = threadIdx.x, lane = tid & 63, wid = tid >> 6;
  const float* srow = scores + (size_t)blockIdx.x * S_;
  float* wrow = wout + (size_t)blockIdx.x * S_;
  f32x4 v0 = *(const f32x4*)&srow[tid * 4];
  f32x4 v1 = *(const f32x4*)&srow[1024 + tid * 4];
  float mx = fmaxf(fmaxf(fmaxf(v0[0], v0[1]), fmaxf(v0[2], v0[3])),
                   fmaxf(fmaxf(v1[0], v1[1]), fmaxf(v1[2], v1[3])));
#pragma unroll
  for (int o = 32; o; o >>= 1) mx = fmaxf(mx, __shfl_xor(mx, o));
  if (lane == 0) rA[wid] = mx;
  __syncthreads();
  mx = fmaxf(fmaxf(rA[0], rA[1]), fmaxf(rA[2], rA[3]));
  float sum = 0.f;
#pragma unroll
  for (int i = 0; i < 4; ++i) { v0[i] = __expf(v0[i] - mx); sum += v0[i]; }
#pragma unroll
  for (int i = 0; i < 4; ++i) { v1[i] = __expf(v1[i] - mx); sum += v1[i]; }
#pragma unroll
  for (int o = 32; o; o >>= 1) sum += __shfl_xor(sum, o);
  if (lane == 0) rB[wid] = sum;
  __syncthreads();
  sum = rB[0] + rB[1] + rB[2] + rB[3];
  const float inv = 1.0f / sum;
#pragma unroll
  for (int i = 0; i < 4; ++i) { v0[i] *= inv; v1[i] *= inv; }
  *(f32x4*)&wrow[tid * 4] = v0;
  *(f32x4*)&wrow[1024 + tid * 4] = v1;
}

// ---------------------------------------------------------------------------
// pool partials over 32-row chunks (coalesced bf16x8)
// ---------------------------------------------------------------------------
__global__ __launch_bounds__(256)
void pool_partial(const bf16_t* __restrict__ X, const float* __restrict__ w,
                  float* __restrict__ partials) {
  __shared__ float sm[2][1024];
  const int tid = threadIdx.x;
  const int chunk = blockIdx.x, b = blockIdx.y;
  const int s0 = chunk * 32;
  const int dc = (tid & 127) * 8;
  const int sp = tid >> 7;
  const int h = dc >> 6;
  const float* wrow = w + ((size_t)b * H_ + h) * S_ + s0;
  const bf16_t* Xb = X + ((size_t)b * S_ + s0) * D_ + dc;
  float acc[8] = {};
  for (int s = sp; s < 32; s += 2) {
    bf16x8 xv = *(const bf16x8*)&Xb[(size_t)s * D_];
    float wt = wrow[s];
#pragma unroll
    for (int j = 0; j < 8; ++j) acc[j] += wt * (float)xv[j];
  }
#pragma unroll
  for (int j = 0; j < 8; ++j) sm[sp][dc + j] = acc[j];
  __syncthreads();
  const int d0 = tid * 4;
  f32x4 r;
#pragma unroll
  for (int j = 0; j < 4; ++j) r[j] = sm[0][d0 + j] + sm[1][d0 + j];
  *(f32x4*)&partials[((size_t)chunk * B_ + b) * D_ + d0] = r;
}

__global__ __launch_bounds__(256)
void pool_reduce(const float* __restrict__ partials, float* __restrict__ pooled) {
  const int idx = blockIdx.x * 256 + threadIdx.x;
  float s = 0.f;
#pragma unroll 8
  for (int c = 0; c < 64; ++c) s += partials[(size_t)c * (B_ * D_) + idx];
  pooled[idx] = s;
}

// ---------------------------------------------------------------------------
extern "C" void kernel_launch(void* const* d_in, const int* in_sizes, int n_in,
                              void* d_out, int out_size, void* d_ws, size_t ws_size,
                              hipStream_t stream) {
  const float* hs   = (const float*)d_in[0];
  const float* mask = (const float*)d_in[1];
  const float* Wq   = (const float*)d_in[2];
  const float* bq   = (const float*)d_in[3];
  const float* Wqa  = (const float*)d_in[4];
  const float* bqa  = (const float*)d_in[5];
  const float* Wk   = (const float*)d_in[6];
  const float* bk   = (const float*)d_in[7];
  const float* Wka  = (const float*)d_in[8];
  const float* bka  = (const float*)d_in[9];
  const float* Wt   = (const float*)d_in[10];
  const float* bt   = (const float*)d_in[11];

  char* ws = (char*)d_ws;
  float*  pq    = (float*)(ws + (64u << 10));
  float*  pk    = (float*)(ws + (128u << 10));
  bf16_t* bqac  = (bf16_t*)(ws + (192u << 10));
  bf16_t* bkac  = (bf16_t*)(ws + (192u << 10) + 64);
  bf16_t* maskc = (bf16_t*)(ws + (256u << 10));
  bf16_t* WqaT  = (bf16_t*)(ws + (1u << 20));
  bf16_t* WkaT  = (bf16_t*)(ws + (1u << 20) + 32768);
  bf16_t* WqT   = (bf16_t*)(ws + (2u << 20));
  bf16_t* WkT   = (bf16_t*)(ws + (4u << 20));
  bf16_t* WtT   = (bf16_t*)(ws + (6u << 20));
  bf16_t* hsb   = (bf16_t*)(ws + (8u << 20));
  bf16_t* mq    = (bf16_t*)(ws + (8u << 20) + ((size_t)64 << 20));
  bf16_t* mqk   = (bf16_t*)(ws + (8u << 20) + ((size_t)128 << 20));
  float* scores = (float*)(ws + (8u << 20) + ((size_t)192 << 20));
  float* wsm    = (float*)(ws + (8u << 20) + ((size_t)194 << 20));
  float* parts  = (float*)(ws + (8u << 20) + ((size_t)196 << 20));

  // prep (merged launches)
  f32_to_bf16<<<16384, 256, 0, stream>>>(hs, hsb);
  conv_misc<<<129, 256, 0, stream>>>(bqa, bka, mask, bqac, bkac, maskc);
  transpose1024_all<<<dim3(16, 16, 3), 256, 0, stream>>>(Wq, Wk, Wt, WqT, WkT, WtT);
  transpose_small_all<<<8, 256, 0, stream>>>(Wqa, Wka, WqaT, WkaT);

  // mixed_q = hs @ Wq + bq
  gemm_bt<0><<<2048, 256, 0, stream>>>(hsb, WqT, bq, mq, nullptr, nullptr, nullptr);

  score_kernel<<<512, 256, 0, stream>>>(mq, WqaT, bqac, maskc, scores);
  softmax_rows<<<256, 256, 0, stream>>>(scores, wsm);
  pool_partial<<<dim3(64, 16), 256, 0, stream>>>(mq, wsm, parts);
  pool_reduce<<<64, 256, 0, stream>>>(parts, pq);

  // mixed_qk = (hs @ Wk + bk) * pooled_q
  gemm_bt<1><<<2048, 256, 0, stream>>>(hsb, WkT, bk, mqk, pq, nullptr, nullptr);

  score_kernel<<<512, 256, 0, stream>>>(mqk, WkaT, bkac, maskc, scores);
  softmax_rows<<<256, 256, 0, stream>>>(scores, wsm);
  pool_partial<<<dim3(64, 16), 256, 0, stream>>>(mqk, wsm, parts);
  pool_reduce<<<64, 256, 0, stream>>>(parts, pk);

  // out = (mq * pk) @ Wt + bt + mixed_q   (weighted fused into A-staging)
  gemm_bt<2><<<2048, 256, 0, stream>>>(mq, WtT, bt, d_out, nullptr, mq, pk);
}